// Round 4
// baseline (1499.234 us; speedup 1.0000x reference)
//
#include <hip/hip_runtime.h>

// MimiEuclideanCodebook — numpy-bit-exact path, fused main kernel.
// d2 = (x2 - 2*(x@e^T)) + e2, argmin over K=2048 (first-min), gather.
// x@e^T as OpenBLAS sgemm: per output one fp32 FMA chain, k=0..255 ascending.
// x2/e2 as numpy pairwise_sum (8 accumulators per 128-block, tree combine).
// embed = es / max(u,1e-5) via IEEE fp32 div.
// ws use: 2.36 MB only (embed, e2, x2) at base of d_ws.

typedef float f32x4 __attribute__((ext_vector_type(4)));

#define D_DIM 256
#define N_ROWS 65536
#define K_CODES 2048
#define BMR 32      // rows per block
#define BNC 256     // codes per col-tile
#define BKC 32      // k-chunk
#define NCT 8       // col tiles
#define VQ_EPS 1e-5f

// ---------------- prep: embed = embed_sum / clip(usage) -----------------------
__global__ void prep_embed(const float* __restrict__ es, const float* __restrict__ us,
                           float* __restrict__ embed) {
    int i = blockIdx.x * 256 + threadIdx.x;      // 524288 total
    int k = i >> 8;
    float u = fmaxf(us[k], VQ_EPS);
    embed[i] = es[i] / u;                         // IEEE fp32 div == np bitwise
}

// numpy pairwise sum of squares over 256: two 128-blocks, each 8 accumulators
// r[j] = sum_i a[j+8i]^2 ascending, tree ((r0+r1)+(r2+r3))+((r4+r5)+(r6+r7)),
// then block0 + block1. 16 lanes per row.
__device__ __forceinline__ void np_sumsq_16lane(const float* a, float* out, int g) {
#pragma clang fp contract(off)
    int j = g & 7, h = g >> 3;
    const float* p = a + h * 128;
    float t = p[j];
    float r = t * t;
#pragma unroll
    for (int i = 1; i < 16; ++i) { float v = p[j + 8 * i]; r += v * v; }
    r += __shfl_xor(r, 1);
    r += __shfl_xor(r, 2);
    r += __shfl_xor(r, 4);
    float other = __shfl_xor(r, 8);
    if (g == 0) *out = r + other;                 // fl(block0 + block1)
}

__global__ void prep_e2(const float* __restrict__ embed, float* __restrict__ e2) {
    int gid = blockIdx.x * 256 + threadIdx.x;     // 2048 codes * 16 lanes
    int k = gid >> 4;
    np_sumsq_16lane(embed + k * D_DIM, e2 + k, threadIdx.x & 15);
}

__global__ void prep_x2(const float* __restrict__ x, float* __restrict__ x2) {
    int gid = blockIdx.x * 256 + threadIdx.x;     // 65536 rows * 16 lanes
    int r = gid >> 4;
    np_sumsq_16lane(x + r * D_DIM, x2 + r, threadIdx.x & 15);
}

// ---------------- fused main: distances + global argmin + idx + quantized -----
__launch_bounds__(256, 3)
__global__ void vq_main(const float* __restrict__ x, const float* __restrict__ embed,
                        const float* __restrict__ es, const float* __restrict__ us,
                        const float* __restrict__ e2, const float* __restrict__ x2,
                        float* __restrict__ out) {
    __shared__ float lA[BMR][36];                 // 32 rows x 32 k (pad 36)
    __shared__ float lB[BKC][260];                // 32 k x 256 codes (pad 260)
    __shared__ int lidx[BMR];

    const int m_base = blockIdx.x * BMR;
    const int tid = threadIdx.x;
    const int lane = tid & 63;
    const int wid = tid >> 6;
    const int row0 = wid * 8;                     // wave owns 8 rows

    float run_bv[8];
    int run_bi[8];
#pragma unroll
    for (int r = 0; r < 8; ++r) { run_bv[r] = __builtin_inff(); run_bi[r] = 0; }

    f32x4 pA;                                     // A chunk: 32x32 = 256 vec4, 1/thread
    f32x4 pB[8];                                  // B chunk: 256x32 = 2048 vec4, 8/thread

    auto gload = [&](int it) {                    // it = ct*8 + kc
        int ct = it >> 3, kc = it & 7;
        {
            int row = tid >> 3, kq = tid & 7;
            pA = *reinterpret_cast<const f32x4*>(&x[(m_base + row) * D_DIM + kc * BKC + kq * 4]);
        }
#pragma unroll
        for (int p = 0; p < 8; ++p) {
            int code = p * 32 + (tid >> 3), kq = tid & 7;
            pB[p] = *reinterpret_cast<const f32x4*>(&embed[(ct * BNC + code) * D_DIM + kc * BKC + kq * 4]);
        }
    };

    gload(0);
#pragma unroll 1
    for (int ct = 0; ct < NCT; ++ct) {
        float acc[8][4];
#pragma unroll
        for (int r = 0; r < 8; ++r)
#pragma unroll
            for (int c = 0; c < 4; ++c) acc[r][c] = 0.0f;

#pragma unroll 1
        for (int kc = 0; kc < 8; ++kc) {
            __syncthreads();                      // prior LDS readers done
            {
                int row = tid >> 3, kq = tid & 7;
                *reinterpret_cast<f32x4*>(&lA[row][kq * 4]) = pA;
            }
#pragma unroll
            for (int p = 0; p < 8; ++p) {
                int code = p * 32 + (tid >> 3), kq = tid & 7;
#pragma unroll
                for (int j = 0; j < 4; ++j) lB[kq * 4 + j][code] = pB[p][j];
            }
            __syncthreads();                      // LDS visible
            int it = ct * 8 + kc;
            if (it < 63) gload(it + 1);           // prefetch next chunk under compute
#pragma unroll
            for (int k4 = 0; k4 < 8; ++k4) {
                // 64 lanes read contiguous 16B each -> conflict-free b128
                f32x4 b0 = *reinterpret_cast<const f32x4*>(&lB[k4 * 4 + 0][lane * 4]);
                f32x4 b1 = *reinterpret_cast<const f32x4*>(&lB[k4 * 4 + 1][lane * 4]);
                f32x4 b2 = *reinterpret_cast<const f32x4*>(&lB[k4 * 4 + 2][lane * 4]);
                f32x4 b3 = *reinterpret_cast<const f32x4*>(&lB[k4 * 4 + 3][lane * 4]);
#pragma unroll
                for (int rr = 0; rr < 8; ++rr) {
                    f32x4 a4 = *reinterpret_cast<const f32x4*>(&lA[row0 + rr][k4 * 4]);
#pragma unroll
                    for (int c = 0; c < 4; ++c) {
                        float t = acc[rr][c];     // single chain, k ascending
                        t = __builtin_fmaf(a4[0], b0[c], t);
                        t = __builtin_fmaf(a4[1], b1[c], t);
                        t = __builtin_fmaf(a4[2], b2[c], t);
                        t = __builtin_fmaf(a4[3], b3[c], t);
                        acc[rr][c] = t;
                    }
                }
            }
        }

        // ---- per-ct epilogue: d2 in np op order, tile argmin, merge ----------
        {
#pragma clang fp contract(off)
            float e2v[4];
#pragma unroll
            for (int c = 0; c < 4; ++c) e2v[c] = e2[ct * BNC + lane * 4 + c];
#pragma unroll
            for (int rr = 0; rr < 8; ++rr) {
                float xv = x2[m_base + row0 + rr];    // wave-uniform
                float bv = 0.f; int bi = 0;
#pragma unroll
                for (int c = 0; c < 4; ++c) {
                    float d2 = (xv - 2.0f * acc[rr][c]) + e2v[c];  // fl(fl(x2-2xe)+e2)
                    int idx = ct * BNC + lane * 4 + c;
                    if (c == 0 || d2 < bv) { bv = d2; bi = idx; }  // ascending codes
                }
#pragma unroll
                for (int s = 1; s < 64; s <<= 1) {    // 64-lane allreduce-min butterfly
                    float ov = __shfl_xor(bv, s);
                    int oi = __shfl_xor(bi, s);
                    if (ov < bv || (ov == bv && oi < bi)) { bv = ov; bi = oi; }
                }
                // uniform across lanes; earlier ct wins ties via strict <
                if (bv < run_bv[rr]) { run_bv[rr] = bv; run_bi[rr] = bi; }
            }
        }
    }

    // ---- final: indices + quantized (recompute embed row via IEEE div) -------
#pragma unroll
    for (int rr = 0; rr < 8; ++rr)
        if (lane == rr) {
            lidx[row0 + rr] = run_bi[rr];
            out[m_base + row0 + rr] = (float)run_bi[rr];
        }
    __syncthreads();                              // lidx visible to all waves

    float* outq = out + N_ROWS;
#pragma unroll
    for (int p = 0; p < 8; ++p) {                 // 32 rows x 64 vec4 = 2048 vec4
        int idx = p * 256 + tid;
        int row = idx >> 6, q = idx & 63;
        int bi = lidx[row];
        float u = fmaxf(us[bi], VQ_EPS);
        f32x4 v = *reinterpret_cast<const f32x4*>(&es[bi * D_DIM + q * 4]);
        f32x4 o;
#pragma unroll
        for (int j = 0; j < 4; ++j) o[j] = v[j] / u;   // IEEE div == np bitwise
        *reinterpret_cast<f32x4*>(&outq[(m_base + row) * D_DIM + q * 4]) = o;
    }
}

extern "C" void kernel_launch(void* const* d_in, const int* in_sizes, int n_in,
                              void* d_out, int out_size, void* d_ws, size_t ws_size,
                              hipStream_t stream) {
    const float* x = (const float*)d_in[0];       // [65536, 256]
    const float* es = (const float*)d_in[1];      // [2048, 256]
    const float* us = (const float*)d_in[2];      // [2048]
    float* out = (float*)d_out;

    char* w = (char*)d_ws;
    float* embed = (float*)(w);                   // 2,097,152 B
    float* e2    = (float*)(w + 2097152);         //     8,192 B
    float* x2    = (float*)(w + 2105344);         //   262,144 B  (total 2.36 MB)

    hipLaunchKernelGGL(prep_embed, dim3(2048), dim3(256), 0, stream, es, us, embed);
    hipLaunchKernelGGL(prep_e2, dim3(128), dim3(256), 0, stream, embed, e2);
    hipLaunchKernelGGL(prep_x2, dim3(4096), dim3(256), 0, stream, x, x2);
    hipLaunchKernelGGL(vq_main, dim3(N_ROWS / BMR), dim3(256), 0, stream,
                       x, embed, es, us, e2, x2, out);
}